// Round 1
// baseline (41654.489 us; speedup 1.0000x reference)
//
#include <hip/hip_runtime.h>
#include <hip/hip_cooperative_groups.h>

namespace cg = cooperative_groups;

// ---------------------------------------------------------------------------
// 2-layer GRU (Keras reset_after=true), B=64, T=1024, D=U=512.
// Persistent cooperative kernel:
//  - 256 WGs = {2 batch-groups of 32 rows} x {2 cells} x {64 column-slices of 8 h-cols}
//  - gate weights pre-packed per-WG into LDS in MFMA B-frag layout, as bf16 hi/lo
//  - hidden state exchanged via __device__ globals (bf16 hi/lo, double-buffered)
//  - one grid.sync per timestep: iteration k computes h0[k] (cell0) and h1[k-1]
//    (cell1) concurrently; total T+1 iterations.
//  - split-bf16 (hi+lo) MFMA: 3 mfma per tile => ~fp32 accuracy.
// ---------------------------------------------------------------------------

typedef __bf16 bf16x8 __attribute__((ext_vector_type(8)));
typedef float  f32x4  __attribute__((ext_vector_type(4)));
typedef short  short8 __attribute__((ext_vector_type(8)));

#define T_STEPS 1024
#define NWG 256
#define NTHR 256
// LDS: Bhi 24576*2 + Blo 24576*2 + acc 1024*4 + hprev 256*4 + bias 32*4
#define SMEM_BYTES (98304 + 4096 + 1024 + 128)

__device__ __align__(16) unsigned short g_xhi[64LL * 1024 * 512];
__device__ __align__(16) unsigned short g_xlo[64LL * 1024 * 512];
// [cell][hi/lo][parity][64][512]
__device__ __align__(16) unsigned short g_h[2 * 2 * 2 * 64 * 512];

__device__ __forceinline__ int h_idx(int cell, int hl, int par, int m, int j) {
    return ((((cell * 2 + hl) * 2 + par) * 64 + m) * 512 + j);
}

__device__ __forceinline__ void f2hilo(float f, unsigned short& hi, unsigned short& lo) {
    __bf16 h = (__bf16)f;               // RNE
    float  fh = (float)h;
    __bf16 l = (__bf16)(f - fh);        // residual, next ~8 mantissa bits
    hi = __builtin_bit_cast(unsigned short, h);
    lo = __builtin_bit_cast(unsigned short, l);
}

__device__ __forceinline__ f32x4 mfma16(bf16x8 a, bf16x8 b, f32x4 c) {
    return __builtin_amdgcn_mfma_f32_16x16x32_bf16(a, b, c, 0, 0, 0);
}

__global__ void __launch_bounds__(NTHR, 1) gru_persistent(
    const float* __restrict__ x,  const float* __restrict__ W0,
    const float* __restrict__ U0, const float* __restrict__ b0,
    const float* __restrict__ W1, const float* __restrict__ U1,
    const float* __restrict__ b1, float* __restrict__ out)
{
    extern __shared__ char smem[];
    unsigned short* sBhi = (unsigned short*)smem;          // 24576 elems
    unsigned short* sBlo = sBhi + 24576;                   // 24576 elems
    float* sAcc   = (float*)(smem + 98304);                // [1024]: zr[32][16] | xh[32][8] | hh[32][8]
    float* sHprev = sAcc + 1024;                           // [256] = [32][8]
    float* sBias  = sHprev + 256;                          // [32]

    const int wg    = blockIdx.x;
    const int g     = wg >> 7;        // batch group: rows [g*32, g*32+32)
    const int cell  = (wg >> 6) & 1;  // 0 or 1
    const int slice = wg & 63;        // 8 h-cols per slice
    const int c0    = slice * 8;
    const int tid   = threadIdx.x;

    cg::grid_group grid = cg::this_grid();

    // ---- init 1: x -> bf16 hi/lo (grid-stride, whole grid) ----
    {
        const long long NT = 64LL * 1024 * 512;
        const long long stride = (long long)NWG * NTHR * 4;
        for (long long i = ((long long)wg * NTHR + tid) * 4; i < NT; i += stride) {
            float4 v = *(const float4*)(x + i);
            unsigned short ha, la, hb, lb, hc, lc, hd, ld;
            f2hilo(v.x, ha, la); f2hilo(v.y, hb, lb);
            f2hilo(v.z, hc, lc); f2hilo(v.w, hd, ld);
            ushort4 hv; hv.x = ha; hv.y = hb; hv.z = hc; hv.w = hd;
            ushort4 lv; lv.x = la; lv.y = lb; lv.z = lc; lv.w = ld;
            *(ushort4*)(g_xhi + i) = hv;
            *(ushort4*)(g_xlo + i) = lv;
        }
    }
    // ---- init 2: zero h buffers ----
    {
        unsigned long long* p = (unsigned long long*)g_h;
        const int n64 = 2 * 2 * 2 * 64 * 512 / 4;   // 131072 u64
        for (int i = wg * NTHR + tid; i < n64; i += NWG * NTHR) p[i] = 0ull;
    }
    // ---- init 3: pre-pack this WG's weight slice into LDS (B-frag layout) ----
    {
        const float* Wm = cell ? W1 : W0;
        const float* Um = cell ? U1 : U0;
        for (int e = tid; e < 24576; e += NTHR) {
            const int pass = e / 12288;        // 0: W (input), 1: U (recurrent)
            const int rem  = e % 12288;
            int j, gcol;
            if (rem < 8192) {                  // ntile0: [z cols 0..7 | r cols 0..7]
                const int ks = rem >> 9, r2 = rem & 511;
                const int entry = r2 >> 3, i = r2 & 7;
                const int col = entry & 15, kch = entry >> 4;
                j = ks * 32 + kch * 8 + i;
                gcol = (col < 8) ? (c0 + col) : (512 + c0 + col - 8);
            } else {                           // ntile1: [h cols 0..7], packed (32 entries)
                const int r2 = rem - 8192;
                const int ks = r2 >> 8, r3 = r2 & 255;
                const int entry = r3 >> 3, i = r3 & 7;
                const int col = entry & 7, kch = entry >> 3;
                j = ks * 32 + kch * 8 + i;
                gcol = 1024 + c0 + col;
            }
            const float v = (pass ? Um : Wm)[j * 1536 + gcol];
            f2hilo(v, sBhi[e], sBlo[e]);
        }
    }
    // ---- init 4: biases + hprev ----
    {
        const float* b = cell ? b1 : b0;       // b[0..1535]=bi, b[1536..]=br
        if (tid < 32) {
            const int col = tid & 7, sec = tid >> 3;
            float v;
            if (sec == 0)      v = b[c0 + col] + b[1536 + c0 + col];               // z: bi+br
            else if (sec == 1) v = b[512 + c0 + col] + b[1536 + 512 + c0 + col];   // r: bi+br
            else if (sec == 2) v = b[1024 + c0 + col];                             // xh: bi
            else               v = b[1536 + 1024 + c0 + col];                      // hh: br
            sBias[tid] = v;
        }
        sHprev[tid] = 0.f;
    }
    __syncthreads();

    const int lane  = tid & 63;
    const int mtile = (tid >> 6) & 1;   // waves 0,1 / 2,3
    const int ntile = tid >> 7;         // 0: zr-tile, 1: h-tile
    const int lcol  = lane & 15;
    const int kch   = lane >> 4;
    const int arow  = g * 32 + mtile * 16 + lcol;  // global batch row this lane loads for A

    short8 z8 = {0, 0, 0, 0, 0, 0, 0, 0};
    const bf16x8 bzero = __builtin_bit_cast(bf16x8, z8);

    for (int k = 0; k <= T_STEPS; ++k) {
        grid.sync();
        const bool active = cell ? (k >= 1) : (k < T_STEPS);
        if (!active) continue;

        const int pin = (k - 1) & 1;   // parity holding h0[k-1] / h-state inputs
        const unsigned short *A0hi, *A0lo, *A1hi, *A1lo;
        if (cell == 0) {
            const long long xo = ((long long)arow * 1024 + k) * 512;
            A0hi = g_xhi + xo;                     A0lo = g_xlo + xo;
            A1hi = g_h + h_idx(0, 0, pin, arow, 0); A1lo = g_h + h_idx(0, 1, pin, arow, 0);
        } else {
            A0hi = g_h + h_idx(0, 0, pin, arow, 0);     A0lo = g_h + h_idx(0, 1, pin, arow, 0);
            A1hi = g_h + h_idx(1, 0, k & 1, arow, 0);   A1lo = g_h + h_idx(1, 1, k & 1, arow, 0);
        }

        f32x4 acc_zr = {0.f, 0.f, 0.f, 0.f};
        f32x4 acc_xh = {0.f, 0.f, 0.f, 0.f};
        f32x4 acc_hh = {0.f, 0.f, 0.f, 0.f};

        for (int pass = 0; pass < 2; ++pass) {
            const unsigned short* Ahi = pass ? A1hi : A0hi;
            const unsigned short* Alo = pass ? A1lo : A0lo;
            if (ntile == 0) {
                #pragma unroll 4
                for (int ks = 0; ks < 16; ++ks) {
                    bf16x8 ah = *(const bf16x8*)(Ahi + ks * 32 + kch * 8);
                    bf16x8 al = *(const bf16x8*)(Alo + ks * 32 + kch * 8);
                    const int o = pass * 12288 + ks * 512 + lane * 8;
                    bf16x8 bh = *(const bf16x8*)(sBhi + o);
                    bf16x8 bl = *(const bf16x8*)(sBlo + o);
                    acc_zr = mfma16(ah, bh, acc_zr);
                    acc_zr = mfma16(ah, bl, acc_zr);
                    acc_zr = mfma16(al, bh, acc_zr);
                }
            } else {
                #pragma unroll 4
                for (int ks = 0; ks < 16; ++ks) {
                    bf16x8 ah = *(const bf16x8*)(Ahi + ks * 32 + kch * 8);
                    bf16x8 al = *(const bf16x8*)(Alo + ks * 32 + kch * 8);
                    bf16x8 bh = bzero, bl = bzero;
                    if (lcol < 8) {
                        const int e = kch * 8 + lcol;
                        const int o = pass * 12288 + 8192 + ks * 256 + e * 8;
                        bh = *(const bf16x8*)(sBhi + o);
                        bl = *(const bf16x8*)(sBlo + o);
                    }
                    f32x4 acc = pass ? acc_hh : acc_xh;
                    acc = mfma16(ah, bh, acc);
                    acc = mfma16(ah, bl, acc);
                    acc = mfma16(al, bh, acc);
                    if (pass) acc_hh = acc; else acc_xh = acc;
                }
            }
        }

        // ---- epilogue: accs -> LDS, gates, h update, publish ----
        {
            const int drow = mtile * 16 + (lane >> 4) * 4;  // D: col=lane&15, row=quad*4+reg
            if (ntile == 0) {
                #pragma unroll
                for (int r2 = 0; r2 < 4; ++r2) sAcc[(drow + r2) * 16 + lcol] = acc_zr[r2];
            } else if (lcol < 8) {
                #pragma unroll
                for (int r2 = 0; r2 < 4; ++r2) {
                    sAcc[512 + (drow + r2) * 8 + lcol] = acc_xh[r2];
                    sAcc[768 + (drow + r2) * 8 + lcol] = acc_hh[r2];
                }
            }
            __syncthreads();

            const int ml  = tid >> 3;   // 0..31 (row within group)
            const int col = tid & 7;    // h-col within slice
            const float zp = sAcc[ml * 16 + col]     + sBias[col];
            const float rp = sAcc[ml * 16 + 8 + col] + sBias[8 + col];
            const float z = 1.f / (1.f + __expf(-zp));
            const float r = 1.f / (1.f + __expf(-rp));
            const float xh = sAcc[512 + ml * 8 + col] + sBias[16 + col];
            const float hh = sAcc[768 + ml * 8 + col] + sBias[24 + col];
            const float ct = tanhf(xh + r * hh);
            const float hp = sHprev[tid];
            const float hn = z * hp + (1.f - z) * ct;
            sHprev[tid] = hn;

            const int pw = cell ? ((k - 1) & 1) : (k & 1);
            const int gm = g * 32 + ml;
            const int gj = c0 + col;
            unsigned short hi_, lo_;
            f2hilo(hn, hi_, lo_);
            g_h[h_idx(cell, 0, pw, gm, gj)] = hi_;
            g_h[h_idx(cell, 1, pw, gm, gj)] = lo_;
            if (cell && k == T_STEPS) out[gm * 512 + gj] = hn;   // h1[T-1]
        }
    }
}

extern "C" void kernel_launch(void* const* d_in, const int* in_sizes, int n_in,
                              void* d_out, int out_size, void* d_ws, size_t ws_size,
                              hipStream_t stream) {
    (void)in_sizes; (void)n_in; (void)d_ws; (void)ws_size; (void)out_size;
    const float* x  = (const float*)d_in[0];
    const float* W0 = (const float*)d_in[1];
    const float* U0 = (const float*)d_in[2];
    const float* b0 = (const float*)d_in[3];
    const float* W1 = (const float*)d_in[4];
    const float* U1 = (const float*)d_in[5];
    const float* b1 = (const float*)d_in[6];
    float* out = (float*)d_out;

    hipFuncSetAttribute((const void*)gru_persistent,
                        hipFuncAttributeMaxDynamicSharedMemorySize, SMEM_BYTES);
    void* args[] = {&x, &W0, &U0, &b0, &W1, &U1, &b1, &out};
    hipLaunchCooperativeKernel((const void*)gru_persistent, dim3(NWG), dim3(NTHR),
                               args, SMEM_BYTES, stream);
}

// Round 2
// 16522.379 us; speedup vs baseline: 2.5211x; 2.5211x over previous
//
#include <hip/hip_runtime.h>

// ---------------------------------------------------------------------------
// 2-layer GRU (Keras reset_after=true), B=64, T=1024, D=U=512.
// Persistent cooperative kernel, custom cross-XCD barrier (no cg::grid::sync).
//  - 256 WGs = {2 batch-groups of 32 rows} x {2 cells} x {64 column-slices}
//  - weights pre-packed per-WG into LDS (MFMA B-frag layout) as bf16 hi/lo
//  - h exchanged via full-history global buffers, packed u32 = (bf16hi<<16)|bf16lo
//    producers: agent-scope (sc1, L2-bypass) relaxed atomic stores
//    consumers: normal cached loads (addresses are virgin per step -> no stale L2)
//  - barrier: two-level monotone counters + epoch word, all relaxed agent atomics;
//    ordering via s_waitcnt vmcnt(0); zero L2 writeback/invalidate per step.
//  - split-bf16 (hi+lo) MFMA: 3 mfma per tile => ~fp32 accuracy.
// ---------------------------------------------------------------------------

typedef __bf16 bf16x8 __attribute__((ext_vector_type(8)));
typedef float  f32x4  __attribute__((ext_vector_type(4)));
typedef unsigned int uint4v __attribute__((ext_vector_type(4)));

#define T_STEPS 1024
#define NWG 256
#define NTHR 256
// LDS: Bhi 49152 + Blo 49152 + acc 4096 + hprev 1024 + bias 128 + misc 16
#define SMEM_BYTES (98304 + 4096 + 1024 + 128 + 16)

// h0[k] at slot k+1 (slot 0 = zeros); h1[k] at slot k+1. 134 MB each.
__device__ __align__(16) unsigned int g_h0[1025LL * 64 * 512];
__device__ __align__(16) unsigned int g_h1[1025LL * 64 * 512];
// barrier state (BSS zero; monotone across calls, offset by E0 read at start)
__device__ unsigned int g_leaf[8 * 64];   // one counter per 256B line
__device__ unsigned int g_root[64];
__device__ unsigned int g_epoch[64];

__device__ __forceinline__ void f2hilo(float f, unsigned short& hi, unsigned short& lo) {
    __bf16 h = (__bf16)f;               // RNE
    float  fh = (float)h;
    __bf16 l = (__bf16)(f - fh);        // residual, next ~8 mantissa bits
    hi = __builtin_bit_cast(unsigned short, h);
    lo = __builtin_bit_cast(unsigned short, l);
}

__device__ __forceinline__ f32x4 mfma16(bf16x8 a, bf16x8 b, f32x4 c) {
    return __builtin_amdgcn_mfma_f32_16x16x32_bf16(a, b, c, 0, 0, 0);
}

// 8 consecutive packed u32 (hi<<16|lo) -> hi-frag, lo-frag
__device__ __forceinline__ void unpack8(const unsigned int* p, bf16x8& ah, bf16x8& al) {
    uint4v v0 = *(const uint4v*)p;
    uint4v v1 = *(const uint4v*)(p + 4);
    uint4v h, l;
    h.x = __builtin_amdgcn_perm(v0.y, v0.x, 0x07060302u);
    h.y = __builtin_amdgcn_perm(v0.w, v0.z, 0x07060302u);
    h.z = __builtin_amdgcn_perm(v1.y, v1.x, 0x07060302u);
    h.w = __builtin_amdgcn_perm(v1.w, v1.z, 0x07060302u);
    l.x = __builtin_amdgcn_perm(v0.y, v0.x, 0x05040100u);
    l.y = __builtin_amdgcn_perm(v0.w, v0.z, 0x05040100u);
    l.z = __builtin_amdgcn_perm(v1.y, v1.x, 0x05040100u);
    l.w = __builtin_amdgcn_perm(v1.w, v1.z, 0x05040100u);
    ah = __builtin_bit_cast(bf16x8, h);
    al = __builtin_bit_cast(bf16x8, l);
}

// 8 consecutive fp32 -> hi-frag, lo-frag (on-the-fly split)
__device__ __forceinline__ void cvt8(const float* p, bf16x8& ah, bf16x8& al) {
    float4 a = *(const float4*)p;
    float4 b = *(const float4*)(p + 4);
    float f[8] = {a.x, a.y, a.z, a.w, b.x, b.y, b.z, b.w};
    bf16x8 h, l;
    #pragma unroll
    for (int i = 0; i < 8; ++i) {
        __bf16 hv = (__bf16)f[i];
        h[i] = hv;
        l[i] = (__bf16)(f[i] - (float)hv);
    }
    ah = h; al = l;
}

__global__ void __launch_bounds__(NTHR, 1) gru_persistent(
    const float* __restrict__ x,  const float* __restrict__ W0,
    const float* __restrict__ U0, const float* __restrict__ b0,
    const float* __restrict__ W1, const float* __restrict__ U1,
    const float* __restrict__ b1, float* __restrict__ out)
{
    extern __shared__ char smem[];
    unsigned short* sBhi = (unsigned short*)smem;          // 24576 elems
    unsigned short* sBlo = sBhi + 24576;                   // 24576 elems
    float* sAcc   = (float*)(smem + 98304);                // [1024]
    float* sHprev = sAcc + 1024;                           // [256]
    float* sBias  = sHprev + 256;                          // [32]
    unsigned int* sE0 = (unsigned int*)(sBias + 32);       // [1]

    const int wg    = blockIdx.x;
    const int g     = wg >> 7;        // batch group: rows [g*32, g*32+32)
    const int cell  = (wg >> 6) & 1;
    const int slice = wg & 63;
    const int c0    = slice * 8;
    const int tid   = threadIdx.x;

    // kill stale L2 lines from a previous call (cheap, once per launch)
    __builtin_amdgcn_fence(__ATOMIC_ACQUIRE, "agent");

    // ---- init: epoch base ----
    if (tid == 0)
        sE0[0] = __hip_atomic_load(&g_epoch[0], __ATOMIC_RELAXED, __HIP_MEMORY_SCOPE_AGENT);

    // ---- init: zero own region of slot 0 (h[-1] = 0) ----
    {
        const int ml = tid >> 3, col = tid & 7;
        unsigned int* dst = (cell ? g_h1 : g_h0)
                          + (long long)(g * 32 + ml) * 512 + (c0 + col);
        __hip_atomic_store(dst, 0u, __ATOMIC_RELAXED, __HIP_MEMORY_SCOPE_AGENT);
    }

    // ---- init: pre-pack this WG's weight slice into LDS (B-frag layout) ----
    {
        const float* Wm = cell ? W1 : W0;
        const float* Um = cell ? U1 : U0;
        for (int e = tid; e < 24576; e += NTHR) {
            const int pass = e / 12288;        // 0: W (input), 1: U (recurrent)
            const int rem  = e % 12288;
            int j, gcol;
            if (rem < 8192) {                  // ntile0: [z cols 0..7 | r cols 0..7]
                const int ks = rem >> 9, r2 = rem & 511;
                const int entry = r2 >> 3, i = r2 & 7;
                const int col = entry & 15, kch = entry >> 4;
                j = ks * 32 + kch * 8 + i;
                gcol = (col < 8) ? (c0 + col) : (512 + c0 + col - 8);
            } else {                           // ntile1: [h cols 0..7], packed
                const int r2 = rem - 8192;
                const int ks = r2 >> 8, r3 = r2 & 255;
                const int entry = r3 >> 3, i = r3 & 7;
                const int col = entry & 7, kch = entry >> 3;
                j = ks * 32 + kch * 8 + i;
                gcol = 1024 + c0 + col;
            }
            const float v = (pass ? Um : Wm)[j * 1536 + gcol];
            f2hilo(v, sBhi[e], sBlo[e]);
        }
    }
    // ---- init: biases + hprev ----
    {
        const float* b = cell ? b1 : b0;
        if (tid < 32) {
            const int col = tid & 7, sec = tid >> 3;
            float v;
            if (sec == 0)      v = b[c0 + col] + b[1536 + c0 + col];
            else if (sec == 1) v = b[512 + c0 + col] + b[1536 + 512 + c0 + col];
            else if (sec == 2) v = b[1024 + c0 + col];
            else               v = b[1536 + 1024 + c0 + col];
            sBias[tid] = v;
        }
        sHprev[tid] = 0.f;
    }
    __syncthreads();
    const unsigned int E0 = sE0[0];

    const int lane  = tid & 63;
    const int mtile = (tid >> 6) & 1;
    const int ntile = tid >> 7;
    const int lcol  = lane & 15;
    const int kch   = lane >> 4;
    const int arow  = g * 32 + mtile * 16 + lcol;

    bf16x8 bzero = {};

    for (int k = 0; k <= T_STEPS; ++k) {
        // ---- barrier: arrive (drains own publishes) + wait on epoch ----
        __syncthreads();                      // compiler emits vmcnt(0) before s_barrier
        const unsigned int target = E0 + (unsigned int)k + 1u;
        if (tid == 0) {
            asm volatile("s_waitcnt vmcnt(0)" ::: "memory");
            unsigned int o = __hip_atomic_fetch_add(&g_leaf[(wg & 7) * 64], 1u,
                                __ATOMIC_RELAXED, __HIP_MEMORY_SCOPE_AGENT);
            if (o == 32u * target - 1u) {
                unsigned int r = __hip_atomic_fetch_add(&g_root[0], 1u,
                                    __ATOMIC_RELAXED, __HIP_MEMORY_SCOPE_AGENT);
                if (r == 8u * target - 1u)
                    __hip_atomic_store(&g_epoch[0], target,
                                       __ATOMIC_RELAXED, __HIP_MEMORY_SCOPE_AGENT);
            }
        }
        while ((int)(__hip_atomic_load(&g_epoch[0], __ATOMIC_RELAXED,
                                       __HIP_MEMORY_SCOPE_AGENT) - target) < 0)
            __builtin_amdgcn_s_sleep(1);
        asm volatile("" ::: "memory");

        const bool active = cell ? (k >= 1) : (k < T_STEPS);
        if (!active) continue;

        // ---- A-operand sources for this iteration ----
        const float* A0x = nullptr;
        const unsigned int *A0p = nullptr, *A1p;
        if (cell == 0) {
            A0x = x + ((long long)arow * 1024 + k) * 512;
            A1p = g_h0 + ((long long)k * (64 * 512)) + arow * 512;        // h0[k-1]
        } else {
            A0p = g_h0 + ((long long)k * (64 * 512)) + arow * 512;        // h0[k-1]
            A1p = g_h1 + ((long long)(k - 1) * (64 * 512)) + arow * 512;  // h1[k-2]
        }

        f32x4 acc_zr = {0.f, 0.f, 0.f, 0.f};
        f32x4 acc_xh = {0.f, 0.f, 0.f, 0.f};
        f32x4 acc_hh = {0.f, 0.f, 0.f, 0.f};

        for (int pass = 0; pass < 2; ++pass) {
            const unsigned int* Ap = pass ? A1p : A0p;
            if (ntile == 0) {
                #pragma unroll 4
                for (int ks = 0; ks < 16; ++ks) {
                    bf16x8 ah, al;
                    if (pass == 0 && cell == 0) cvt8(A0x + ks * 32 + kch * 8, ah, al);
                    else                        unpack8(Ap + ks * 32 + kch * 8, ah, al);
                    const int o = pass * 12288 + ks * 512 + lane * 8;
                    bf16x8 bh = *(const bf16x8*)(sBhi + o);
                    bf16x8 bl = *(const bf16x8*)(sBlo + o);
                    acc_zr = mfma16(ah, bh, acc_zr);
                    acc_zr = mfma16(ah, bl, acc_zr);
                    acc_zr = mfma16(al, bh, acc_zr);
                }
            } else {
                #pragma unroll 4
                for (int ks = 0; ks < 16; ++ks) {
                    bf16x8 ah, al;
                    if (pass == 0 && cell == 0) cvt8(A0x + ks * 32 + kch * 8, ah, al);
                    else                        unpack8(Ap + ks * 32 + kch * 8, ah, al);
                    bf16x8 bh = bzero, bl = bzero;
                    if (lcol < 8) {
                        const int e = kch * 8 + lcol;
                        const int o = pass * 12288 + 8192 + ks * 256 + e * 8;
                        bh = *(const bf16x8*)(sBhi + o);
                        bl = *(const bf16x8*)(sBlo + o);
                    }
                    f32x4 acc = pass ? acc_hh : acc_xh;
                    acc = mfma16(ah, bh, acc);
                    acc = mfma16(ah, bl, acc);
                    acc = mfma16(al, bh, acc);
                    if (pass) acc_hh = acc; else acc_xh = acc;
                }
            }
        }

        // ---- epilogue: accs -> LDS, gates, h update, publish ----
        {
            const int drow = mtile * 16 + (lane >> 4) * 4;  // D: col=lane&15, row=quad*4+reg
            if (ntile == 0) {
                #pragma unroll
                for (int r2 = 0; r2 < 4; ++r2) sAcc[(drow + r2) * 16 + lcol] = acc_zr[r2];
            } else if (lcol < 8) {
                #pragma unroll
                for (int r2 = 0; r2 < 4; ++r2) {
                    sAcc[512 + (drow + r2) * 8 + lcol] = acc_xh[r2];
                    sAcc[768 + (drow + r2) * 8 + lcol] = acc_hh[r2];
                }
            }
            __syncthreads();

            const int ml  = tid >> 3;
            const int col = tid & 7;
            const float zp = sAcc[ml * 16 + col]     + sBias[col];
            const float rp = sAcc[ml * 16 + 8 + col] + sBias[8 + col];
            const float z = 1.f / (1.f + __expf(-zp));
            const float r = 1.f / (1.f + __expf(-rp));
            const float xh = sAcc[512 + ml * 8 + col] + sBias[16 + col];
            const float hh = sAcc[768 + ml * 8 + col] + sBias[24 + col];
            const float ct = tanhf(xh + r * hh);
            const float hp = sHprev[tid];
            const float hn = z * hp + (1.f - z) * ct;
            sHprev[tid] = hn;

            const int gm = g * 32 + ml;
            const int gj = c0 + col;
            unsigned short hi_, lo_;
            f2hilo(hn, hi_, lo_);
            const unsigned int pk = ((unsigned int)hi_ << 16) | (unsigned int)lo_;
            const long long slot = cell ? (long long)k : (long long)(k + 1);
            unsigned int* dst = (cell ? g_h1 : g_h0)
                              + slot * (64 * 512) + (long long)gm * 512 + gj;
            __hip_atomic_store(dst, pk, __ATOMIC_RELAXED, __HIP_MEMORY_SCOPE_AGENT);
            if (cell && k == T_STEPS) out[gm * 512 + gj] = hn;   // h1[T-1]
        }
    }
}

extern "C" void kernel_launch(void* const* d_in, const int* in_sizes, int n_in,
                              void* d_out, int out_size, void* d_ws, size_t ws_size,
                              hipStream_t stream) {
    (void)in_sizes; (void)n_in; (void)d_ws; (void)ws_size; (void)out_size;
    const float* x  = (const float*)d_in[0];
    const float* W0 = (const float*)d_in[1];
    const float* U0 = (const float*)d_in[2];
    const float* b0 = (const float*)d_in[3];
    const float* W1 = (const float*)d_in[4];
    const float* U1 = (const float*)d_in[5];
    const float* b1 = (const float*)d_in[6];
    float* out = (float*)d_out;

    hipFuncSetAttribute((const void*)gru_persistent,
                        hipFuncAttributeMaxDynamicSharedMemorySize, SMEM_BYTES);
    void* args[] = {&x, &W0, &U0, &b0, &W1, &U1, &b1, &out};
    hipLaunchCooperativeKernel((const void*)gru_persistent, dim3(NWG), dim3(NTHR),
                               args, SMEM_BYTES, stream);
}

// Round 3
// 10701.909 us; speedup vs baseline: 3.8922x; 1.5439x over previous
//
#include <hip/hip_runtime.h>

// ---------------------------------------------------------------------------
// 2-layer GRU (Keras reset_after=true), B=64, T=1024, D=U=512.
// Persistent cooperative kernel with DATAFLOW sync (no per-step grid barrier).
//  - 256 WGs = {2 batch-groups g of 32 rows} x {2 cells} x {64 column-slices}
//  - weights pre-packed per-WG into LDS (MFMA B-frag layout) as bf16 hi/lo
//  - h exchanged via full-history global buffers, packed u32=(bf16hi<<16)|bf16lo
//    producers: relaxed agent-scope stores (bypass L2); consumers: normal cached
//    loads (virgin addresses per launch; start-of-kernel acquire fence kills
//    stale lines from previous launch)
//  - sync: per-(cell,g) 64-word flag lines, ring of 8, monotone values k+1.
//    producer: ONE agent store after vmcnt-drain. consumer: wave-0 polls the
//    64-word line with one coalesced agent load + ballot, then __syncthreads.
//    No RMWs in steady state. One-time RMW-tree barrier only to init flags.
//  - split-bf16 (hi+lo) MFMA: 3 mfma per tile => ~fp32 accuracy.
// ---------------------------------------------------------------------------

typedef __bf16 bf16x8 __attribute__((ext_vector_type(8)));
typedef float  f32x4  __attribute__((ext_vector_type(4)));
typedef unsigned int uint4v __attribute__((ext_vector_type(4)));

#define T_STEPS 1024
#define NWG 256
#define NTHR 256
#define SMEM_BYTES (98304 + 4096 + 1024 + 128 + 16)

// h0[k] at slot k+1 (slot 0 = zeros); h1[t] at slot t+1. 134 MB each.
__device__ __align__(16) unsigned int g_h0[1025LL * 64 * 512];
__device__ __align__(16) unsigned int g_h1[1025LL * 64 * 512];
// one-time init barrier state (BSS zero; monotone across launches)
__device__ unsigned int g_leaf[8 * 64];
__device__ unsigned int g_root[64];
__device__ unsigned int g_epoch[64];
// dataflow flags: [cell][g][ring8][slice] -- zeroed at start of each launch
__device__ __align__(256) unsigned int g_flag[2][2][8][64];

__device__ __forceinline__ void f2hilo(float f, unsigned short& hi, unsigned short& lo) {
    __bf16 h = (__bf16)f;
    float  fh = (float)h;
    __bf16 l = (__bf16)(f - fh);
    hi = __builtin_bit_cast(unsigned short, h);
    lo = __builtin_bit_cast(unsigned short, l);
}

__device__ __forceinline__ f32x4 mfma16(bf16x8 a, bf16x8 b, f32x4 c) {
    return __builtin_amdgcn_mfma_f32_16x16x32_bf16(a, b, c, 0, 0, 0);
}

__device__ __forceinline__ void unpack8(const unsigned int* p, bf16x8& ah, bf16x8& al) {
    uint4v v0 = *(const uint4v*)p;
    uint4v v1 = *(const uint4v*)(p + 4);
    uint4v h, l;
    h.x = __builtin_amdgcn_perm(v0.y, v0.x, 0x07060302u);
    h.y = __builtin_amdgcn_perm(v0.w, v0.z, 0x07060302u);
    h.z = __builtin_amdgcn_perm(v1.y, v1.x, 0x07060302u);
    h.w = __builtin_amdgcn_perm(v1.w, v1.z, 0x07060302u);
    l.x = __builtin_amdgcn_perm(v0.y, v0.x, 0x05040100u);
    l.y = __builtin_amdgcn_perm(v0.w, v0.z, 0x05040100u);
    l.z = __builtin_amdgcn_perm(v1.y, v1.x, 0x05040100u);
    l.w = __builtin_amdgcn_perm(v1.w, v1.z, 0x05040100u);
    ah = __builtin_bit_cast(bf16x8, h);
    al = __builtin_bit_cast(bf16x8, l);
}

__device__ __forceinline__ void cvt8(const float* p, bf16x8& ah, bf16x8& al) {
    float4 a = *(const float4*)p;
    float4 b = *(const float4*)(p + 4);
    float f[8] = {a.x, a.y, a.z, a.w, b.x, b.y, b.z, b.w};
    bf16x8 h, l;
    #pragma unroll
    for (int i = 0; i < 8; ++i) {
        __bf16 hv = (__bf16)f[i];
        h[i] = hv;
        l[i] = (__bf16)(f[i] - (float)hv);
    }
    ah = h; al = l;
}

// one GEMM pass (verified round-2 logic, parameterized)
__device__ __forceinline__ void gemm_pass(
    bool useX, int pass, int ntile, int lane, int lcol, int kch,
    const float* A0x, const unsigned int* Ap,
    const unsigned short* sBhi, const unsigned short* sBlo,
    f32x4& acc_zr, f32x4& acc_xh, f32x4& acc_hh)
{
    bf16x8 bzero = {};
    if (ntile == 0) {
        #pragma unroll 4
        for (int ks = 0; ks < 16; ++ks) {
            bf16x8 ah, al;
            if (useX) cvt8(A0x + ks * 32 + kch * 8, ah, al);
            else      unpack8(Ap + ks * 32 + kch * 8, ah, al);
            const int o = pass * 12288 + ks * 512 + lane * 8;
            bf16x8 bh = *(const bf16x8*)(sBhi + o);
            bf16x8 bl = *(const bf16x8*)(sBlo + o);
            acc_zr = mfma16(ah, bh, acc_zr);
            acc_zr = mfma16(ah, bl, acc_zr);
            acc_zr = mfma16(al, bh, acc_zr);
        }
    } else {
        #pragma unroll 4
        for (int ks = 0; ks < 16; ++ks) {
            bf16x8 ah, al;
            if (useX) cvt8(A0x + ks * 32 + kch * 8, ah, al);
            else      unpack8(Ap + ks * 32 + kch * 8, ah, al);
            bf16x8 bh = bzero, bl = bzero;
            if (lcol < 8) {
                const int e = kch * 8 + lcol;
                const int o = pass * 12288 + 8192 + ks * 256 + e * 8;
                bh = *(const bf16x8*)(sBhi + o);
                bl = *(const bf16x8*)(sBlo + o);
            }
            f32x4 acc = pass ? acc_hh : acc_xh;
            acc = mfma16(ah, bh, acc);
            acc = mfma16(ah, bl, acc);
            acc = mfma16(al, bh, acc);
            if (pass) acc_hh = acc; else acc_xh = acc;
        }
    }
}

// epilogue (verified round-2 logic): accs -> gates -> hn (per thread ml,col)
__device__ __forceinline__ float epilogue_hn(
    int tid, int mtile, int ntile, int lane, int lcol,
    const f32x4& acc_zr, const f32x4& acc_xh, const f32x4& acc_hh,
    float* sAcc, float* sHprev, const float* sBias)
{
    const int drow = mtile * 16 + (lane >> 4) * 4;
    if (ntile == 0) {
        #pragma unroll
        for (int r2 = 0; r2 < 4; ++r2) sAcc[(drow + r2) * 16 + lcol] = acc_zr[r2];
    } else if (lcol < 8) {
        #pragma unroll
        for (int r2 = 0; r2 < 4; ++r2) {
            sAcc[512 + (drow + r2) * 8 + lcol] = acc_xh[r2];
            sAcc[768 + (drow + r2) * 8 + lcol] = acc_hh[r2];
        }
    }
    __syncthreads();
    const int ml  = tid >> 3;
    const int col = tid & 7;
    const float zp = sAcc[ml * 16 + col]     + sBias[col];
    const float rp = sAcc[ml * 16 + 8 + col] + sBias[8 + col];
    const float z = 1.f / (1.f + __expf(-zp));
    const float r = 1.f / (1.f + __expf(-rp));
    const float xh = sAcc[512 + ml * 8 + col] + sBias[16 + col];
    const float hh = sAcc[768 + ml * 8 + col] + sBias[24 + col];
    const float ct = tanhf(xh + r * hh);
    const float hp = sHprev[tid];
    const float hn = z * hp + (1.f - z) * ct;
    sHprev[tid] = hn;
    return hn;
}

// wave-0 polls one 64-word flag line; whole WG released by __syncthreads
__device__ __forceinline__ void wait_one(const unsigned int* P, unsigned int target, int tid) {
    if (tid < 64) {
        while (true) {
            unsigned int v = __hip_atomic_load(P + tid, __ATOMIC_RELAXED,
                                               __HIP_MEMORY_SCOPE_AGENT);
            if (__ballot(v >= target) == ~0ull) break;
            __builtin_amdgcn_s_sleep(1);
        }
    }
    __syncthreads();
}

__device__ __forceinline__ void wait_two(const unsigned int* Pa, unsigned int ta,
                                         const unsigned int* Pb, unsigned int tb, int tid) {
    if (tid < 64) {
        bool da = false, db = false;
        while (true) {
            if (!da) {
                unsigned int v = __hip_atomic_load(Pa + tid, __ATOMIC_RELAXED,
                                                   __HIP_MEMORY_SCOPE_AGENT);
                da = (__ballot(v >= ta) == ~0ull);
            }
            if (!db) {
                unsigned int v = __hip_atomic_load(Pb + tid, __ATOMIC_RELAXED,
                                                   __HIP_MEMORY_SCOPE_AGENT);
                db = (__ballot(v >= tb) == ~0ull);
            }
            if (da && db) break;
            __builtin_amdgcn_s_sleep(1);
        }
    }
    __syncthreads();
}

__global__ void __launch_bounds__(NTHR, 1) gru_persistent(
    const float* __restrict__ x,  const float* __restrict__ W0,
    const float* __restrict__ U0, const float* __restrict__ b0,
    const float* __restrict__ W1, const float* __restrict__ U1,
    const float* __restrict__ b1, float* __restrict__ out)
{
    extern __shared__ char smem[];
    unsigned short* sBhi = (unsigned short*)smem;
    unsigned short* sBlo = sBhi + 24576;
    float* sAcc   = (float*)(smem + 98304);
    float* sHprev = sAcc + 1024;
    float* sBias  = sHprev + 256;
    unsigned int* sE0 = (unsigned int*)(sBias + 32);

    const int wg    = blockIdx.x;
    const int g     = wg >> 7;
    const int cell  = (wg >> 6) & 1;
    const int slice = wg & 63;
    const int c0    = slice * 8;
    const int tid   = threadIdx.x;

    // kill stale L1/L2 lines from a previous launch
    __builtin_amdgcn_fence(__ATOMIC_ACQUIRE, "agent");

    if (tid == 0)
        sE0[0] = __hip_atomic_load(&g_epoch[0], __ATOMIC_RELAXED, __HIP_MEMORY_SCOPE_AGENT);

    // zero own region of slot 0 (h[-1] = 0)
    {
        const int ml = tid >> 3, col = tid & 7;
        unsigned int* dst = (cell ? g_h1 : g_h0)
                          + (long long)(g * 32 + ml) * 512 + (c0 + col);
        __hip_atomic_store(dst, 0u, __ATOMIC_RELAXED, __HIP_MEMORY_SCOPE_AGENT);
    }
    // zero dataflow flags (2048 words across 256 WGs)
    if (tid < 8) {
        unsigned int* f = &g_flag[0][0][0][0];
        __hip_atomic_store(f + wg * 8 + tid, 0u, __ATOMIC_RELAXED, __HIP_MEMORY_SCOPE_AGENT);
    }

    // pre-pack weight slice into LDS (B-frag layout), bf16 hi/lo
    {
        const float* Wm = cell ? W1 : W0;
        const float* Um = cell ? U1 : U0;
        for (int e = tid; e < 24576; e += NTHR) {
            const int pass = e / 12288;
            const int rem  = e % 12288;
            int j, gcol;
            if (rem < 8192) {
                const int ks = rem >> 9, r2 = rem & 511;
                const int entry = r2 >> 3, i = r2 & 7;
                const int col = entry & 15, kch = entry >> 4;
                j = ks * 32 + kch * 8 + i;
                gcol = (col < 8) ? (c0 + col) : (512 + c0 + col - 8);
            } else {
                const int r2 = rem - 8192;
                const int ks = r2 >> 8, r3 = r2 & 255;
                const int entry = r3 >> 3, i = r3 & 7;
                const int col = entry & 7, kch = entry >> 3;
                j = ks * 32 + kch * 8 + i;
                gcol = 1024 + c0 + col;
            }
            const float v = (pass ? Um : Wm)[j * 1536 + gcol];
            f2hilo(v, sBhi[e], sBlo[e]);
        }
    }
    // biases + hprev
    {
        const float* b = cell ? b1 : b0;
        if (tid < 32) {
            const int col = tid & 7, sec = tid >> 3;
            float v;
            if (sec == 0)      v = b[c0 + col] + b[1536 + c0 + col];
            else if (sec == 1) v = b[512 + c0 + col] + b[1536 + 512 + c0 + col];
            else if (sec == 2) v = b[1024 + c0 + col];
            else               v = b[1536 + 1024 + c0 + col];
            sBias[tid] = v;
        }
        sHprev[tid] = 0.f;
    }
    __syncthreads();
    const unsigned int E0 = sE0[0];

    // ---- one-time grid barrier (flags + slot0 now initialized everywhere) ----
    {
        const unsigned int target = E0 + 1u;
        if (tid == 0) {
            asm volatile("s_waitcnt vmcnt(0)" ::: "memory");
            unsigned int o = __hip_atomic_fetch_add(&g_leaf[(wg & 7) * 64], 1u,
                                __ATOMIC_RELAXED, __HIP_MEMORY_SCOPE_AGENT);
            if (o == 32u * target - 1u) {
                unsigned int r = __hip_atomic_fetch_add(&g_root[0], 1u,
                                    __ATOMIC_RELAXED, __HIP_MEMORY_SCOPE_AGENT);
                if (r == 8u * target - 1u)
                    __hip_atomic_store(&g_epoch[0], target,
                                       __ATOMIC_RELAXED, __HIP_MEMORY_SCOPE_AGENT);
            }
        }
        while ((int)(__hip_atomic_load(&g_epoch[0], __ATOMIC_RELAXED,
                                       __HIP_MEMORY_SCOPE_AGENT) - target) < 0)
            __builtin_amdgcn_s_sleep(1);
        asm volatile("" ::: "memory");
        __syncthreads();
    }

    const int lane  = tid & 63;
    const int mtile = (tid >> 6) & 1;
    const int ntile = tid >> 7;
    const int lcol  = lane & 15;
    const int kch   = lane >> 4;
    const int arow  = g * 32 + mtile * 16 + lcol;

    if (cell == 0) {
        unsigned int* const myflag = &g_flag[0][g][0][0];
        for (int k = 0; k < T_STEPS; ++k) {
            // pass 0: x @ W (no dependency) -- overlaps peer lag
            f32x4 acc_zr = {0.f, 0.f, 0.f, 0.f};
            f32x4 acc_xh = {0.f, 0.f, 0.f, 0.f};
            f32x4 acc_hh = {0.f, 0.f, 0.f, 0.f};
            const float* A0x = x + ((long long)arow * 1024 + k) * 512;
            gemm_pass(true, 0, ntile, lane, lcol, kch, A0x, nullptr,
                      sBhi, sBlo, acc_zr, acc_xh, acc_hh);

            // wait for h0[k-1] (all 64 slices of this g)
            if (k > 0)
                wait_one(&g_flag[0][g][(k - 1) & 7][0], (unsigned int)k, tid);

            // pass 1: h0[k-1] @ U
            const unsigned int* A1p = g_h0 + ((long long)k * (64 * 512)) + arow * 512;
            gemm_pass(false, 1, ntile, lane, lcol, kch, nullptr, A1p,
                      sBhi, sBlo, acc_zr, acc_xh, acc_hh);

            const float hn = epilogue_hn(tid, mtile, ntile, lane, lcol,
                                         acc_zr, acc_xh, acc_hh, sAcc, sHprev, sBias);
            // publish h0[k] into slot k+1
            {
                const int ml = tid >> 3, col = tid & 7;
                unsigned short hi_, lo_;
                f2hilo(hn, hi_, lo_);
                const unsigned int pk = ((unsigned int)hi_ << 16) | (unsigned int)lo_;
                unsigned int* dst = g_h0 + (long long)(k + 1) * (64 * 512)
                                  + (long long)(g * 32 + ml) * 512 + (c0 + col);
                __hip_atomic_store(dst, pk, __ATOMIC_RELAXED, __HIP_MEMORY_SCOPE_AGENT);
            }
            __syncthreads();   // drains each wave's vmem before barrier
            if (tid == 0)
                __hip_atomic_store(myflag + ((k & 7) * 64) + slice, (unsigned int)(k + 1),
                                   __ATOMIC_RELAXED, __HIP_MEMORY_SCOPE_AGENT);
        }
    } else {
        unsigned int* const myflag = &g_flag[1][g][0][0];
        for (int t = 0; t < T_STEPS; ++t) {
            // wait: h1[t-1] (own group, t>=1) and h0[t] (cell0 group)
            if (t > 0)
                wait_two(&g_flag[1][g][(t - 1) & 7][0], (unsigned int)t,
                         &g_flag[0][g][t & 7][0], (unsigned int)(t + 1), tid);
            else
                wait_one(&g_flag[0][g][0][0], 1u, tid);

            f32x4 acc_zr = {0.f, 0.f, 0.f, 0.f};
            f32x4 acc_xh = {0.f, 0.f, 0.f, 0.f};
            f32x4 acc_hh = {0.f, 0.f, 0.f, 0.f};
            const unsigned int* A0p = g_h0 + ((long long)(t + 1) * (64 * 512)) + arow * 512;
            const unsigned int* A1p = g_h1 + ((long long)t * (64 * 512)) + arow * 512;
            gemm_pass(false, 0, ntile, lane, lcol, kch, nullptr, A0p,
                      sBhi, sBlo, acc_zr, acc_xh, acc_hh);
            gemm_pass(false, 1, ntile, lane, lcol, kch, nullptr, A1p,
                      sBhi, sBlo, acc_zr, acc_xh, acc_hh);

            const float hn = epilogue_hn(tid, mtile, ntile, lane, lcol,
                                         acc_zr, acc_xh, acc_hh, sAcc, sHprev, sBias);
            {
                const int ml = tid >> 3, col = tid & 7;
                unsigned short hi_, lo_;
                f2hilo(hn, hi_, lo_);
                const unsigned int pk = ((unsigned int)hi_ << 16) | (unsigned int)lo_;
                unsigned int* dst = g_h1 + (long long)(t + 1) * (64 * 512)
                                  + (long long)(g * 32 + ml) * 512 + (c0 + col);
                __hip_atomic_store(dst, pk, __ATOMIC_RELAXED, __HIP_MEMORY_SCOPE_AGENT);
                if (t == T_STEPS - 1)
                    out[(g * 32 + ml) * 512 + (c0 + col)] = hn;
            }
            __syncthreads();
            if (tid == 0)
                __hip_atomic_store(myflag + ((t & 7) * 64) + slice, (unsigned int)(t + 1),
                                   __ATOMIC_RELAXED, __HIP_MEMORY_SCOPE_AGENT);
        }
    }
}

extern "C" void kernel_launch(void* const* d_in, const int* in_sizes, int n_in,
                              void* d_out, int out_size, void* d_ws, size_t ws_size,
                              hipStream_t stream) {
    (void)in_sizes; (void)n_in; (void)d_ws; (void)ws_size; (void)out_size;
    const float* x  = (const float*)d_in[0];
    const float* W0 = (const float*)d_in[1];
    const float* U0 = (const float*)d_in[2];
    const float* b0 = (const float*)d_in[3];
    const float* W1 = (const float*)d_in[4];
    const float* U1 = (const float*)d_in[5];
    const float* b1 = (const float*)d_in[6];
    float* out = (float*)d_out;

    hipFuncSetAttribute((const void*)gru_persistent,
                        hipFuncAttributeMaxDynamicSharedMemorySize, SMEM_BYTES);
    void* args[] = {&x, &W0, &U0, &b0, &W1, &U1, &b1, &out};
    hipLaunchCooperativeKernel((const void*)gru_persistent, dim3(NWG), dim3(NTHR),
                               args, SMEM_BYTES, stream);
}

// Round 6
// 9998.997 us; speedup vs baseline: 4.1659x; 1.0703x over previous
//
#include <hip/hip_runtime.h>

// ---------------------------------------------------------------------------
// 2-layer GRU (Keras reset_after=true), B=64, T=1024, D=U=512.
// Persistent kernel (round-3 verified skeleton), dataflow sync via per-clique
// single-word COUNTERS, streaming A-loads (NO register bursts).
//  - 256 WGs = {2 batch-groups g of 32 rows} x {2 cells} x {64 column-slices}
//  - weights pre-packed per-WG into LDS (MFMA B-frag layout) as bf16 hi/lo
//  - h exchanged via full-history global buffers, packed u32=(bf16hi<<16)|bf16lo
//    producers: relaxed agent-scope stores; consumers: normal cached loads
//    (virgin addresses per launch; start-of-kernel acquire fence kills stale)
//  - sync: one u32 counter per (cell,g) clique + a separate cross-consumer
//    counter for cell0->cell1, each on its own 256B line. Producer tid0:
//    fetch_add(+1) after __syncthreads drain. Consumer tid0: single-lane poll
//    with constant-arg backoff sleep -> __syncthreads release.
//  - cell1 runs its own-recurrence GEMM before the cross-wait (overlap).
//  - split-bf16 (hi+lo) MFMA: 3 mfma per tile => ~fp32 accuracy.
//  - kernel_launch checks the cooperative-launch rc and falls back to a plain
//    launch (256 WGs at 1 WG/CU are co-resident regardless).
// ---------------------------------------------------------------------------

typedef __bf16 bf16x8 __attribute__((ext_vector_type(8)));
typedef float  f32x4  __attribute__((ext_vector_type(4)));
typedef unsigned int uint4v __attribute__((ext_vector_type(4)));

#define T_STEPS 1024
#define NWG 256
#define NTHR 256
#define SMEM_BYTES (98304 + 4096 + 1024 + 128 + 32)

// h0[k] at slot k+1 (slot 0 = zeros); h1[t] at slot t+1. 134 MB each.
__device__ __align__(16) unsigned int g_h0[1025LL * 64 * 512];
__device__ __align__(16) unsigned int g_h1[1025LL * 64 * 512];
// one-time init barrier state (BSS zero; monotone across launches)
__device__ unsigned int g_leaf[8 * 64];
__device__ unsigned int g_root[64];
__device__ unsigned int g_epoch[64];
// per-clique step counters, each on its own 256B line; monotone across launches
__device__ __align__(256) unsigned int g_cnt[2][2][64];   // [cell][g]: own-clique waiters
__device__ __align__(256) unsigned int g_cntx[2][64];     // [g]: cell0 progress, cell1 waiters

__device__ __forceinline__ void f2hilo(float f, unsigned short& hi, unsigned short& lo) {
    __bf16 h = (__bf16)f;
    float  fh = (float)h;
    __bf16 l = (__bf16)(f - fh);
    hi = __builtin_bit_cast(unsigned short, h);
    lo = __builtin_bit_cast(unsigned short, l);
}

__device__ __forceinline__ f32x4 mfma16(bf16x8 a, bf16x8 b, f32x4 c) {
    return __builtin_amdgcn_mfma_f32_16x16x32_bf16(a, b, c, 0, 0, 0);
}

__device__ __forceinline__ void unpack8(const unsigned int* p, bf16x8& ah, bf16x8& al) {
    uint4v v0 = *(const uint4v*)p;
    uint4v v1 = *(const uint4v*)(p + 4);
    uint4v h, l;
    h.x = __builtin_amdgcn_perm(v0.y, v0.x, 0x07060302u);
    h.y = __builtin_amdgcn_perm(v0.w, v0.z, 0x07060302u);
    h.z = __builtin_amdgcn_perm(v1.y, v1.x, 0x07060302u);
    h.w = __builtin_amdgcn_perm(v1.w, v1.z, 0x07060302u);
    l.x = __builtin_amdgcn_perm(v0.y, v0.x, 0x05040100u);
    l.y = __builtin_amdgcn_perm(v0.w, v0.z, 0x05040100u);
    l.z = __builtin_amdgcn_perm(v1.y, v1.x, 0x05040100u);
    l.w = __builtin_amdgcn_perm(v1.w, v1.z, 0x05040100u);
    ah = __builtin_bit_cast(bf16x8, h);
    al = __builtin_bit_cast(bf16x8, l);
}

__device__ __forceinline__ void cvt8(const float* p, bf16x8& ah, bf16x8& al) {
    float4 a = *(const float4*)p;
    float4 b = *(const float4*)(p + 4);
    float f[8] = {a.x, a.y, a.z, a.w, b.x, b.y, b.z, b.w};
    bf16x8 h, l;
    #pragma unroll
    for (int i = 0; i < 8; ++i) {
        __bf16 hv = (__bf16)f[i];
        h[i] = hv;
        l[i] = (__bf16)(f[i] - (float)hv);
    }
    ah = h; al = l;
}

// one GEMM pass (verified round-2/3 logic, streaming loads)
__device__ __forceinline__ void gemm_pass(
    bool useX, int pass, int ntile, int lane, int lcol, int kch,
    const float* A0x, const unsigned int* Ap,
    const unsigned short* sBhi, const unsigned short* sBlo,
    f32x4& acc_zr, f32x4& acc_xh, f32x4& acc_hh)
{
    bf16x8 bzero = {};
    if (ntile == 0) {
        #pragma unroll 4
        for (int ks = 0; ks < 16; ++ks) {
            bf16x8 ah, al;
            if (useX) cvt8(A0x + ks * 32 + kch * 8, ah, al);
            else      unpack8(Ap + ks * 32 + kch * 8, ah, al);
            const int o = pass * 12288 + ks * 512 + lane * 8;
            bf16x8 bh = *(const bf16x8*)(sBhi + o);
            bf16x8 bl = *(const bf16x8*)(sBlo + o);
            acc_zr = mfma16(ah, bh, acc_zr);
            acc_zr = mfma16(ah, bl, acc_zr);
            acc_zr = mfma16(al, bh, acc_zr);
        }
    } else {
        #pragma unroll 4
        for (int ks = 0; ks < 16; ++ks) {
            bf16x8 ah, al;
            if (useX) cvt8(A0x + ks * 32 + kch * 8, ah, al);
            else      unpack8(Ap + ks * 32 + kch * 8, ah, al);
            bf16x8 bh = bzero, bl = bzero;
            if (lcol < 8) {
                const int e = kch * 8 + lcol;
                const int o = pass * 12288 + 8192 + ks * 256 + e * 8;
                bh = *(const bf16x8*)(sBhi + o);
                bl = *(const bf16x8*)(sBlo + o);
            }
            f32x4 acc = pass ? acc_hh : acc_xh;
            acc = mfma16(ah, bh, acc);
            acc = mfma16(ah, bl, acc);
            acc = mfma16(al, bh, acc);
            if (pass) acc_hh = acc; else acc_xh = acc;
        }
    }
}

// epilogue (verified): accs -> gates -> hn (per thread ml,col)
__device__ __forceinline__ float epilogue_hn(
    int tid, int mtile, int ntile, int lane, int lcol,
    const f32x4& acc_zr, const f32x4& acc_xh, const f32x4& acc_hh,
    float* sAcc, float* sHprev, const float* sBias)
{
    const int drow = mtile * 16 + (lane >> 4) * 4;
    if (ntile == 0) {
        #pragma unroll
        for (int r2 = 0; r2 < 4; ++r2) sAcc[(drow + r2) * 16 + lcol] = acc_zr[r2];
    } else if (lcol < 8) {
        #pragma unroll
        for (int r2 = 0; r2 < 4; ++r2) {
            sAcc[512 + (drow + r2) * 8 + lcol] = acc_xh[r2];
            sAcc[768 + (drow + r2) * 8 + lcol] = acc_hh[r2];
        }
    }
    __syncthreads();
    const int ml  = tid >> 3;
    const int col = tid & 7;
    const float zp = sAcc[ml * 16 + col]     + sBias[col];
    const float rp = sAcc[ml * 16 + 8 + col] + sBias[8 + col];
    const float z = 1.f / (1.f + __expf(-zp));
    const float r = 1.f / (1.f + __expf(-rp));
    const float xh = sAcc[512 + ml * 8 + col] + sBias[16 + col];
    const float hh = sAcc[768 + ml * 8 + col] + sBias[24 + col];
    const float ct = tanhf(xh + r * hh);
    const float hp = sHprev[tid];
    const float hn = z * hp + (1.f - z) * ct;
    sHprev[tid] = hn;
    return hn;
}

// single-lane counter poll with constant-arg backoff, then release the WG
__device__ __forceinline__ void wait_cnt(unsigned int* C, unsigned int target, int tid) {
    if (tid == 0) {
        int spins = 0;
        while ((int)(__hip_atomic_load(C, __ATOMIC_RELAXED,
                                       __HIP_MEMORY_SCOPE_AGENT) - target) < 0) {
            if (spins < 4) __builtin_amdgcn_s_sleep(1);
            else           __builtin_amdgcn_s_sleep(8);
            ++spins;
        }
    }
    __syncthreads();
}

__global__ void __launch_bounds__(NTHR, 1) gru_persistent(
    const float* __restrict__ x,  const float* __restrict__ W0,
    const float* __restrict__ U0, const float* __restrict__ b0,
    const float* __restrict__ W1, const float* __restrict__ U1,
    const float* __restrict__ b1, float* __restrict__ out)
{
    extern __shared__ char smem[];
    unsigned short* sBhi = (unsigned short*)smem;
    unsigned short* sBlo = sBhi + 24576;
    float* sAcc   = (float*)(smem + 98304);
    float* sHprev = sAcc + 1024;
    float* sBias  = sHprev + 256;
    unsigned int* sE0 = (unsigned int*)(sBias + 32);  // [0]=epoch,[1]=own,[2]=cross

    const int wg    = blockIdx.x;
    const int g     = wg >> 7;
    const int cell  = (wg >> 6) & 1;
    const int slice = wg & 63;
    const int c0    = slice * 8;
    const int tid   = threadIdx.x;

    // kill stale L1/L2 lines from a previous launch
    __builtin_amdgcn_fence(__ATOMIC_ACQUIRE, "agent");

    // counter bases: read before the init grid-barrier (no adds until after it)
    if (tid == 0) {
        sE0[0] = __hip_atomic_load(&g_epoch[0], __ATOMIC_RELAXED, __HIP_MEMORY_SCOPE_AGENT);
        sE0[1] = __hip_atomic_load(&g_cnt[cell][g][0], __ATOMIC_RELAXED, __HIP_MEMORY_SCOPE_AGENT);
        sE0[2] = __hip_atomic_load(&g_cntx[g][0], __ATOMIC_RELAXED, __HIP_MEMORY_SCOPE_AGENT);
    }

    // zero own region of slot 0 (h[-1] = 0)
    {
        const int ml = tid >> 3, col = tid & 7;
        unsigned int* dst = (cell ? g_h1 : g_h0)
                          + (long long)(g * 32 + ml) * 512 + (c0 + col);
        __hip_atomic_store(dst, 0u, __ATOMIC_RELAXED, __HIP_MEMORY_SCOPE_AGENT);
    }

    // pre-pack weight slice into LDS (B-frag layout), bf16 hi/lo
    {
        const float* Wm = cell ? W1 : W0;
        const float* Um = cell ? U1 : U0;
        for (int e = tid; e < 24576; e += NTHR) {
            const int pass = e / 12288;
            const int rem  = e % 12288;
            int j, gcol;
            if (rem < 8192) {
                const int ks = rem >> 9, r2 = rem & 511;
                const int entry = r2 >> 3, i = r2 & 7;
                const int col = entry & 15, kch = entry >> 4;
                j = ks * 32 + kch * 8 + i;
                gcol = (col < 8) ? (c0 + col) : (512 + c0 + col - 8);
            } else {
                const int r2 = rem - 8192;
                const int ks = r2 >> 8, r3 = r2 & 255;
                const int entry = r3 >> 3, i = r3 & 7;
                const int col = entry & 7, kch = entry >> 3;
                j = ks * 32 + kch * 8 + i;
                gcol = 1024 + c0 + col;
            }
            const float v = (pass ? Um : Wm)[j * 1536 + gcol];
            f2hilo(v, sBhi[e], sBlo[e]);
        }
    }
    // biases + hprev
    {
        const float* b = cell ? b1 : b0;
        if (tid < 32) {
            const int col = tid & 7, sec = tid >> 3;
            float v;
            if (sec == 0)      v = b[c0 + col] + b[1536 + c0 + col];
            else if (sec == 1) v = b[512 + c0 + col] + b[1536 + 512 + c0 + col];
            else if (sec == 2) v = b[1024 + c0 + col];
            else               v = b[1536 + 1024 + c0 + col];
            sBias[tid] = v;
        }
        sHprev[tid] = 0.f;
    }
    __syncthreads();
    const unsigned int E0     = sE0[0];
    const unsigned int Cown   = sE0[1];
    const unsigned int Ccross = sE0[2];

    // ---- one-time grid barrier (slot0 zeros + bases now safe everywhere) ----
    {
        const unsigned int target = E0 + 1u;
        if (tid == 0) {
            asm volatile("s_waitcnt vmcnt(0)" ::: "memory");
            unsigned int o = __hip_atomic_fetch_add(&g_leaf[(wg & 7) * 64], 1u,
                                __ATOMIC_RELAXED, __HIP_MEMORY_SCOPE_AGENT);
            if (o == 32u * target - 1u) {
                unsigned int r = __hip_atomic_fetch_add(&g_root[0], 1u,
                                    __ATOMIC_RELAXED, __HIP_MEMORY_SCOPE_AGENT);
                if (r == 8u * target - 1u)
                    __hip_atomic_store(&g_epoch[0], target,
                                       __ATOMIC_RELAXED, __HIP_MEMORY_SCOPE_AGENT);
            }
        }
        while ((int)(__hip_atomic_load(&g_epoch[0], __ATOMIC_RELAXED,
                                       __HIP_MEMORY_SCOPE_AGENT) - target) < 0)
            __builtin_amdgcn_s_sleep(1);
        asm volatile("" ::: "memory");
        __syncthreads();
    }

    const int lane  = tid & 63;
    const int mtile = (tid >> 6) & 1;
    const int ntile = tid >> 7;
    const int lcol  = lane & 15;
    const int kch   = lane >> 4;
    const int arow  = g * 32 + mtile * 16 + lcol;
    const int ml    = tid >> 3;
    const int colw  = tid & 7;

    if (cell == 0) {
        unsigned int* const cnt  = &g_cnt[0][g][0];
        unsigned int* const cntx = &g_cntx[g][0];
        for (int k = 0; k < T_STEPS; ++k) {
            f32x4 acc_zr = {0.f, 0.f, 0.f, 0.f};
            f32x4 acc_xh = {0.f, 0.f, 0.f, 0.f};
            f32x4 acc_hh = {0.f, 0.f, 0.f, 0.f};
            // pass 0: x @ W (no dependency) -- overlaps peer lag
            const float* A0x = x + ((long long)arow * 1024 + k) * 512;
            gemm_pass(true, 0, ntile, lane, lcol, kch, A0x, nullptr,
                      sBhi, sBlo, acc_zr, acc_xh, acc_hh);

            // wait for h0[k-1] (all 64 slices of this g)
            if (k > 0) wait_cnt(cnt, Cown + 64u * (unsigned int)k, tid);

            // pass 1: h0[k-1] @ U (streaming loads)
            const unsigned int* A1p = g_h0 + ((long long)k * (64 * 512)) + arow * 512;
            gemm_pass(false, 1, ntile, lane, lcol, kch, nullptr, A1p,
                      sBhi, sBlo, acc_zr, acc_xh, acc_hh);

            const float hn = epilogue_hn(tid, mtile, ntile, lane, lcol,
                                         acc_zr, acc_xh, acc_hh, sAcc, sHprev, sBias);
            // publish h0[k] into slot k+1
            {
                unsigned short hi_, lo_;
                f2hilo(hn, hi_, lo_);
                const unsigned int pk = ((unsigned int)hi_ << 16) | (unsigned int)lo_;
                unsigned int* dst = g_h0 + (long long)(k + 1) * (64 * 512)
                                  + (long long)(g * 32 + ml) * 512 + (c0 + colw);
                __hip_atomic_store(dst, pk, __ATOMIC_RELAXED, __HIP_MEMORY_SCOPE_AGENT);
            }
            __syncthreads();   // per-wave vmcnt(0) drain before barrier
            if (tid == 0) {
                __hip_atomic_fetch_add(cnt, 1u, __ATOMIC_RELAXED, __HIP_MEMORY_SCOPE_AGENT);
                __hip_atomic_fetch_add(cntx, 1u, __ATOMIC_RELAXED, __HIP_MEMORY_SCOPE_AGENT);
            }
        }
    } else {
        unsigned int* const cnt   = &g_cnt[1][g][0];
        unsigned int* const cntUp = &g_cntx[g][0];
        for (int t = 0; t < T_STEPS; ++t) {
            // wait own clique: h1[t-1]
            if (t > 0) wait_cnt(cnt, Cown + 64u * (unsigned int)t, tid);

            f32x4 acc_zr = {0.f, 0.f, 0.f, 0.f};
            f32x4 acc_xh = {0.f, 0.f, 0.f, 0.f};
            f32x4 acc_hh = {0.f, 0.f, 0.f, 0.f};

            // own-recurrence pass first: h1[t-1] @ U1 (overlaps upstream lag)
            const unsigned int* A1p = g_h1 + ((long long)t * (64 * 512)) + arow * 512;
            gemm_pass(false, 1, ntile, lane, lcol, kch, nullptr, A1p,
                      sBhi, sBlo, acc_zr, acc_xh, acc_hh);

            // wait upstream: h0[t]
            wait_cnt(cntUp, Ccross + 64u * (unsigned int)(t + 1), tid);

            const unsigned int* A0p = g_h0 + ((long long)(t + 1) * (64 * 512)) + arow * 512;
            gemm_pass(false, 0, ntile, lane, lcol, kch, nullptr, A0p,
                      sBhi, sBlo, acc_zr, acc_xh, acc_hh);

            const float hn = epilogue_hn(tid, mtile, ntile, lane, lcol,
                                         acc_zr, acc_xh, acc_hh, sAcc, sHprev, sBias);
            {
                unsigned short hi_, lo_;
                f2hilo(hn, hi_, lo_);
                const unsigned int pk = ((unsigned int)hi_ << 16) | (unsigned int)lo_;
                unsigned int* dst = g_h1 + (long long)(t + 1) * (64 * 512)
                                  + (long long)(g * 32 + ml) * 512 + (c0 + colw);
                __hip_atomic_store(dst, pk, __ATOMIC_RELAXED, __HIP_MEMORY_SCOPE_AGENT);
                if (t == T_STEPS - 1)
                    out[(g * 32 + ml) * 512 + (c0 + colw)] = hn;
            }
            __syncthreads();
            if (tid == 0)
                __hip_atomic_fetch_add(cnt, 1u, __ATOMIC_RELAXED, __HIP_MEMORY_SCOPE_AGENT);
        }
    }
}

extern "C" void kernel_launch(void* const* d_in, const int* in_sizes, int n_in,
                              void* d_out, int out_size, void* d_ws, size_t ws_size,
                              hipStream_t stream) {
    (void)in_sizes; (void)n_in; (void)d_ws; (void)ws_size; (void)out_size;
    const float* x  = (const float*)d_in[0];
    const float* W0 = (const float*)d_in[1];
    const float* U0 = (const float*)d_in[2];
    const float* b0 = (const float*)d_in[3];
    const float* W1 = (const float*)d_in[4];
    const float* U1 = (const float*)d_in[5];
    const float* b1 = (const float*)d_in[6];
    float* out = (float*)d_out;

    (void)hipFuncSetAttribute((const void*)gru_persistent,
                              hipFuncAttributeMaxDynamicSharedMemorySize, SMEM_BYTES);
    void* args[] = {&x, &W0, &U0, &b0, &W1, &U1, &b1, &out};
    hipError_t e = hipLaunchCooperativeKernel((const void*)gru_persistent,
                                              dim3(NWG), dim3(NTHR),
                                              args, SMEM_BYTES, stream);
    if (e != hipSuccess) {
        // 256 WGs at 1 WG/CU on 256 CUs are co-resident under a plain launch too
        gru_persistent<<<dim3(NWG), dim3(NTHR), SMEM_BYTES, stream>>>(
            x, W0, U0, b0, W1, U1, b1, out);
    }
}